// Round 2
// baseline (120.501 us; speedup 1.0000x reference)
//
#include <hip/hip_runtime.h>

// TwoRobots: x1 = x + (A1x + A2x + Bu)*H + w, elementwise over B=1e6 columns.
// Trig identities collapse: Fgx = -KS*dx - CD*vx ; Fgy = -KS*dy - CD*vy.
// Memory-bound: 112 MB/call -> ~18 us floor at 6.3 TB/s.
//
// R2: same as R1 but with clang-native ext_vector_type(4) floats --
// __builtin_nontemporal_load/store rejects HIP_vector_type (float4).
// Agent split across blockIdx.y (grid 977 -> 2x977 blocks: halves the
// wave-quantization tail, doubles resident waves/CU); nontemporal loads and
// stores (every byte touched exactly once -- no reuse to protect in L2/L3).

#define H_STEP 0.05f
#define KSC    2.0f
#define CDC    2.0f

typedef float v4f __attribute__((ext_vector_type(4)));

__global__ __launch_bounds__(256)
void two_robots_kernel(const v4f* __restrict__ x4,
                       const v4f* __restrict__ u4,
                       const v4f* __restrict__ w4,
                       const float* __restrict__ xbar,
                       v4f* __restrict__ out4,
                       int nvec)  // nvec = B/4
{
    const int i = blockIdx.x * blockDim.x + threadIdx.x;
    if (i >= nvec) return;

    const int a  = blockIdx.y;        // agent 0 or 1
    const int rb = a * 4;             // x/w/out row base for this agent
    const int ub = a * 2;             // u row base

    // wave-uniform target position (scalar s_load path)
    const float xt = xbar[a * 4 + 0];
    const float yt = xbar[a * 4 + 1];

    const size_t nv = (size_t)nvec;
    const size_t rbase = (size_t)rb * nv + i;
    const size_t ubase = (size_t)ub * nv + i;

    // 10 streaming loads (issued back-to-back for MLP)
    v4f px = __builtin_nontemporal_load(&x4[rbase + 0 * nv]);
    v4f py = __builtin_nontemporal_load(&x4[rbase + 1 * nv]);
    v4f vx = __builtin_nontemporal_load(&x4[rbase + 2 * nv]);
    v4f vy = __builtin_nontemporal_load(&x4[rbase + 3 * nv]);
    v4f ux = __builtin_nontemporal_load(&u4[ubase + 0 * nv]);
    v4f uy = __builtin_nontemporal_load(&u4[ubase + 1 * nv]);
    v4f w0 = __builtin_nontemporal_load(&w4[rbase + 0 * nv]);
    v4f w1 = __builtin_nontemporal_load(&w4[rbase + 1 * nv]);
    v4f w2 = __builtin_nontemporal_load(&w4[rbase + 2 * nv]);
    v4f w3 = __builtin_nontemporal_load(&w4[rbase + 3 * nv]);

    // vector math over all 4 components at once (ext_vector supports elementwise ops)
    v4f o0 = px + vx * H_STEP + w0;
    v4f o1 = py + vy * H_STEP + w1;
    v4f o2 = vx + (-KSC * (px - xt) - CDC * vx + ux) * H_STEP + w2;
    v4f o3 = vy + (-KSC * (py - yt) - CDC * vy + uy) * H_STEP + w3;

    __builtin_nontemporal_store(o0, &out4[rbase + 0 * nv]);
    __builtin_nontemporal_store(o1, &out4[rbase + 1 * nv]);
    __builtin_nontemporal_store(o2, &out4[rbase + 2 * nv]);
    __builtin_nontemporal_store(o3, &out4[rbase + 3 * nv]);
}

extern "C" void kernel_launch(void* const* d_in, const int* in_sizes, int n_in,
                              void* d_out, int out_size, void* d_ws, size_t ws_size,
                              hipStream_t stream) {
    const float* x    = (const float*)d_in[0];   // (8, B)
    const float* u    = (const float*)d_in[1];   // (4, B)
    const float* w    = (const float*)d_in[2];   // (8, B)
    const float* xbar = (const float*)d_in[3];   // (8,)
    // d_in[4] = t (unused)
    float* out = (float*)d_out;                  // (8, B)

    const int B = in_sizes[0] / 8;               // 1,000,000 (divisible by 4)
    const int nvec = B / 4;
    const int block = 256;
    dim3 grid((nvec + block - 1) / block, 2);

    two_robots_kernel<<<grid, block, 0, stream>>>(
        (const v4f*)x, (const v4f*)u, (const v4f*)w, xbar,
        (v4f*)out, nvec);
}

// Round 3
// 116.490 us; speedup vs baseline: 1.0344x; 1.0344x over previous
//
#include <hip/hip_runtime.h>

// TwoRobots: x1 = x + (A1x + A2x + Bu)*H + w, elementwise over B=1e6 columns.
// Trig identities collapse: Fgx = -KS*dx - CD*vx ; Fgy = -KS*dy - CD*vy.
// Memory-bound: 112 MB/call -> ~17.8 us floor at 6.3 TB/s.
//
// R3: x- and y-coordinate equations are fully independent, so split into
// 4 independent jobs (agent x coord) via blockIdx.y. Each thread: 5 loads +
// 2 stores (7 streams) instead of 10+4 (14 streams) -- zero redundant bytes.
// Tests the HBM row-thrash theory (many 4MB-strided streams/wave). Reverted
// R2's nontemporal hints (measured +3us regression vs R0).

#define H_STEP 0.05f
#define KSC    2.0f
#define CDC    2.0f

__global__ __launch_bounds__(256)
void two_robots_kernel(const float4* __restrict__ x4,
                       const float4* __restrict__ u4,
                       const float4* __restrict__ w4,
                       const float*  __restrict__ xbar,
                       float4* __restrict__ out4,
                       int nvec)  // nvec = B/4
{
    const int i = blockIdx.x * blockDim.x + threadIdx.x;
    if (i >= nvec) return;

    const int job = blockIdx.y;   // 0..3 : (agent<<1) | coord
    const int a   = job >> 1;     // agent 0/1
    const int c   = job & 1;      // coord 0=x, 1=y

    const int pr = a * 4 + c;       // position row in x/w/out
    const int vr = a * 4 + 2 + c;   // velocity row in x/w/out
    const int ur = a * 2 + c;       // control row in u

    // wave-uniform target (scalar s_load path)
    const float t = xbar[a * 4 + c];

    const size_t nv = (size_t)nvec;
    const size_t ip = (size_t)pr * nv + i;
    const size_t iv = (size_t)vr * nv + i;
    const size_t iu = (size_t)ur * nv + i;

    // 5 streaming loads
    float4 p  = x4[ip];
    float4 v  = x4[iv];
    float4 uc = u4[iu];
    float4 wp = w4[ip];
    float4 wv = w4[iv];

    float4 op, ov;
#define LANE(k)                                                              \
    op.k = p.k + v.k * H_STEP + wp.k;                                        \
    ov.k = v.k + (-KSC * (p.k - t) - CDC * v.k + uc.k) * H_STEP + wv.k;
    LANE(x) LANE(y) LANE(z) LANE(w)
#undef LANE

    out4[ip] = op;
    out4[iv] = ov;
}

extern "C" void kernel_launch(void* const* d_in, const int* in_sizes, int n_in,
                              void* d_out, int out_size, void* d_ws, size_t ws_size,
                              hipStream_t stream) {
    const float* x    = (const float*)d_in[0];   // (8, B)
    const float* u    = (const float*)d_in[1];   // (4, B)
    const float* w    = (const float*)d_in[2];   // (8, B)
    const float* xbar = (const float*)d_in[3];   // (8,)
    // d_in[4] = t (unused)
    float* out = (float*)d_out;                  // (8, B)

    const int B = in_sizes[0] / 8;               // 1,000,000 (divisible by 4)
    const int nvec = B / 4;
    const int block = 256;
    dim3 grid((nvec + block - 1) / block, 4);

    two_robots_kernel<<<grid, block, 0, stream>>>(
        (const float4*)x, (const float4*)u, (const float4*)w, xbar,
        (float4*)out, nvec);
}